// Round 16
// baseline (138.222 us; speedup 1.0000x reference)
//
#include <hip/hip_runtime.h>
#include <hip/hip_bf16.h>
#include <math.h>

#define Bn 8192
#define Dn 256
#define Pn 4096

// embn rows are scaled by SCALE so the MFMA accumulator is directly the
// base-2 exponent: acc = sim * log2(e)/TEMP.  exp(sim/TEMP) = 2^acc = one v_exp_f32.
#define SCALE 2.8853900817779268f   // log2(e) / TEMP
#define LN2   0.6931471805599453f

using f16x8 = _Float16 __attribute__((ext_vector_type(8)));
using f16x4 = _Float16 __attribute__((ext_vector_type(4)));
using f32x16 = float __attribute__((ext_vector_type(16)));

// ------- normalize rows (fp32 -> f16; emb scaled by SCALE) + hist + zero s_glob -------
// grid = (Bn+Pn)/4 blocks: rows [0,Bn) = embeddings, [Bn,Bn+Pn) = prototypes.
__global__ void norm_hist_kernel(const float* __restrict__ emb, const float* __restrict__ protos,
                                 const int* __restrict__ cid,
                                 _Float16* __restrict__ embn, _Float16* __restrict__ pron,
                                 float* __restrict__ s_glob, int* __restrict__ hist) {
    __shared__ int h[Pn];
    int gid  = blockIdx.x;
    bool do_hist = (gid < Bn / 256);
    if (do_hist)
        for (int c = threadIdx.x; c < Pn; c += 256) h[c] = 0;

    int row  = gid * 4 + (threadIdx.x >> 6);
    int lane = threadIdx.x & 63;
    const float* in;
    _Float16* out;
    int r;
    float post;
    if (row < Bn) { in = emb;    out = embn; r = row;      post = SCALE; }
    else          { in = protos; out = pron; r = row - Bn; post = 1.0f;  }
    const float4 v = reinterpret_cast<const float4*>(in + (size_t)r * Dn)[lane];
    float ss = v.x * v.x + v.y * v.y + v.z * v.z + v.w * v.w;
#pragma unroll
    for (int m = 1; m <= 32; m <<= 1) ss += __shfl_xor(ss, m);
    float scale = post / fmaxf(sqrtf(ss), 1e-12f);
    f16x4 o;
    o[0] = (_Float16)(v.x * scale);
    o[1] = (_Float16)(v.y * scale);
    o[2] = (_Float16)(v.z * scale);
    o[3] = (_Float16)(v.w * scale);
    reinterpret_cast<f16x4*>(out + (size_t)r * Dn)[lane] = o;

    if (gid < 32) s_glob[gid * 256 + threadIdx.x] = 0.0f;   // zero all 8192 rows

    if (do_hist) {
        __syncthreads();
        atomicAdd(&h[cid[gid * 256 + threadIdx.x]], 1);
        __syncthreads();
        for (int c = threadIdx.x; c < Pn; c += 256)
            hist[gid * Pn + c] = h[c];
    }
}

// ---------------- GEMM + exp-sum: s[row] = sum_p 2^acc ----------------
// SINGLE-STAGE / SINGLE-BARRIER: block = 128 rows x 128 cols, 4 waves x 32 rows
// (32x32x16 MFMA, R12's proven fragment shape). The whole 64 KB B panel is
// staged fragment-major up-front (16 back-to-back global_load_lds per thread,
// deep MLP), ONE __syncthreads, then the entire tile computes barrier-free.
// Removes the per-sub barrier convoy (8 barriers -> 1) that R12/R13 showed
// dominates (all pipes idle at ~43 us regardless of occupancy).
__global__ __launch_bounds__(256, 2)
void gemm_expsum_kernel(const _Float16* __restrict__ embn, const _Float16* __restrict__ pron,
                        float* __restrict__ s_glob) {
    __shared__ _Float16 Bs[64 * 512];     // 64 KB: granule g -> Bs + g*1024 + lane*16
    const int w    = threadIdx.x >> 6;
    const int lane = threadIdx.x & 63;
    const int lo   = lane & 31;
    const int hi   = lane >> 5;
    const int rbase = blockIdx.x * 128 + w * 32;
    const int cbase = blockIdx.y * 128;

    // Stage ALL 64 granules (128 cols x 256 k, fragment-major).
    // granule g = ct*16+kk holds B-frag slice: pron[cbase+ct*32+lo][kk*16+hi*8 ..+8]
#pragma unroll
    for (int i = 0; i < 16; ++i) {
        int g  = w * 16 + i;
        int ct = g >> 4, kk = g & 15;
        const _Float16* gsrc =
            pron + (size_t)(cbase + ct * 32 + lo) * Dn + kk * 16 + hi * 8;
        char* l = (char*)Bs + (g << 10);   // wave-uniform base; +lane*16 implicit
        __builtin_amdgcn_global_load_lds(
            (const __attribute__((address_space(1))) unsigned int*)gsrc,
            (__attribute__((address_space(3))) unsigned int*)l, 16, 0, 0);
    }

    // A fragments: lane lo -> row rbase+lo, elems k = kk*16 + hi*8 + j
    const _Float16* ap = embn + (size_t)(rbase + lo) * Dn + hi * 8;
    f16x8 a[16];
#pragma unroll
    for (int kk = 0; kk < 16; ++kk)
        a[kk] = *reinterpret_cast<const f16x8*>(ap + kk * 16);

    float s[16];
#pragma unroll
    for (int r = 0; r < 16; ++r) s[r] = 0.0f;

    __syncthreads();   // the ONLY barrier: all staged data + a[] resident

#pragma unroll
    for (int ct = 0; ct < 4; ++ct) {
        f32x16 acc;
#pragma unroll
        for (int r = 0; r < 16; ++r) acc[r] = 0.0f;
#pragma unroll
        for (int kk = 0; kk < 16; ++kk) {
            f16x8 b = *reinterpret_cast<const f16x8*>(
                (const char*)Bs + ((ct * 16 + kk) << 10) + (lane << 4));  // lane-linear
            acc = __builtin_amdgcn_mfma_f32_32x32x16_f16(a[kk], b, acc, 0, 0, 0);
        }
#pragma unroll
        for (int r = 0; r < 16; ++r)
            s[r] += __builtin_amdgcn_exp2f(acc[r]);   // acc IS the base-2 exponent
    }

    // C/D: col = lo, row = (r&3)+8*(r>>2)+4*hi. Sum over the 32 col-lanes.
#pragma unroll
    for (int r = 0; r < 16; ++r) {
        float v = s[r];
        v += __shfl_xor(v, 1);
        v += __shfl_xor(v, 2);
        v += __shfl_xor(v, 4);
        v += __shfl_xor(v, 8);
        v += __shfl_xor(v, 16);
        if (lo == 0) {
            int row = rbase + (r & 3) + 8 * (r >> 2) + 4 * hi;
            atomicAdd(&s_glob[row], v);
        }
    }
}

// ------- loss terms: term = ln(S_all - 2^accp) - ln2*accp -------
__global__ void loss_terms_kernel(const _Float16* __restrict__ embn, const _Float16* __restrict__ pron,
                                  const int* __restrict__ cid, const float* __restrict__ s_glob,
                                  float* __restrict__ terms) {
    int row  = blockIdx.x * 4 + (threadIdx.x >> 6);
    int lane = threadIdx.x & 63;
    int c = cid[row];
    f16x4 e = reinterpret_cast<const f16x4*>(embn + (size_t)row * Dn)[lane];
    f16x4 p = reinterpret_cast<const f16x4*>(pron + (size_t)c * Dn)[lane];
    float d = 0.0f;
#pragma unroll
    for (int j = 0; j < 4; ++j) d += (float)e[j] * (float)p[j];
#pragma unroll
    for (int m = 1; m <= 32; m <<= 1) d += __shfl_xor(d, m);
    if (lane == 0) {
        float accp = d;                                        // = pos_sim * log2(e)/TEMP
        float sneg = s_glob[row] - __builtin_amdgcn_exp2f(accp);  // remove positive column
        terms[row] = __logf(sneg) - LN2 * accp;                // = ln(sneg) - pos_sim/TEMP
    }
}

// ------- counts + per-chunk prefix (parallel, 16 blocks) -------
__global__ void counts_pref_kernel(const int* __restrict__ hist, int* __restrict__ counts,
                                   int* __restrict__ pref) {
    int c = blockIdx.x * 256 + threadIdx.x;
    int s = 0;
#pragma unroll
    for (int ch = 0; ch < 32; ++ch) {
        pref[ch * Pn + c] = s;
        s += hist[ch * Pn + c];
    }
    counts[c] = s;
}

// ------- exclusive scan of counts[4096] -> offs (one block, 256 thr x 16) -------
__global__ void offsets_kernel(const int* __restrict__ counts, int* __restrict__ offs) {
    __shared__ int wtot[4];
    int t = threadIdx.x;
    int local[16];
    int run = 0;
#pragma unroll
    for (int j = 0; j < 16; ++j) { local[j] = run; run += counts[t * 16 + j]; }
    int v = run;
#pragma unroll
    for (int d = 1; d < 64; d <<= 1) {
        int u = __shfl_up(v, d);
        if ((t & 63) >= d) v += u;
    }
    if ((t & 63) == 63) wtot[t >> 6] = v;
    __syncthreads();
    int add = 0;
    for (int ww = 0; ww < (t >> 6); ++ww) add += wtot[ww];
    int excl = add + v - run;
#pragma unroll
    for (int j = 0; j < 16; ++j) offs[t * 16 + j] = excl + local[j];
    if (t == 0) offs[Pn] = Bn;
}

// ------- rank within cluster (deterministic) + CSR fill -------
__global__ void rankfill_kernel(const int* __restrict__ cid, const int* __restrict__ pref,
                                const int* __restrict__ offs, int* __restrict__ slist) {
    __shared__ int ids[256];
    int t = threadIdx.x, g = blockIdx.x;
    int i = g * 256 + t;
    int my = cid[i];
    ids[t] = my;
    __syncthreads();
    int r = pref[g * Pn + my];
    for (int j = 0; j < t; ++j) r += (ids[j] == my) ? 1 : 0;
    slist[offs[my] + r] = i;
}

// ------- EMA gather (one wave per cluster) + loss mean on block 0 -------
__global__ void update_loss_kernel(const float* __restrict__ protos, const float* __restrict__ emb,
                                   const int* __restrict__ offs, const int* __restrict__ slist,
                                   const float* __restrict__ terms, float* __restrict__ out) {
    __shared__ float ws2[4];
    float* outp = out + 1;
    int w = threadIdx.x >> 6, lane = threadIdx.x & 63;
    int c = blockIdx.x * 4 + w;
    int off = offs[c], cnt = offs[c + 1] - off;
    float4 p = reinterpret_cast<const float4*>(protos + (size_t)c * Dn)[lane];
    float scale = __powf(0.9f, (float)cnt);
    float4 acc;
    acc.x = p.x * scale; acc.y = p.y * scale; acc.z = p.z * scale; acc.w = p.w * scale;
    for (int j = 0; j < cnt; ++j) {
        int i = slist[off + j];
        float wgt = 0.1f * __powf(0.9f, (float)(cnt - 1 - j));
        float4 e = reinterpret_cast<const float4*>(emb + (size_t)i * Dn)[lane];
        acc.x += wgt * e.x; acc.y += wgt * e.y; acc.z += wgt * e.z; acc.w += wgt * e.w;
    }
    reinterpret_cast<float4*>(outp + (size_t)c * Dn)[lane] = acc;

    if (blockIdx.x == 0) {
        float ssum = 0.0f;
        for (int i = threadIdx.x; i < Bn; i += 256) ssum += terms[i];
#pragma unroll
        for (int m = 1; m <= 32; m <<= 1) ssum += __shfl_xor(ssum, m);
        if ((threadIdx.x & 63) == 0) ws2[threadIdx.x >> 6] = ssum;
        __syncthreads();
        if (threadIdx.x == 0)
            out[0] = (ws2[0] + ws2[1] + ws2[2] + ws2[3]) * (1.0f / (float)Bn);
    }
}

extern "C" void kernel_launch(void* const* d_in, const int* in_sizes, int n_in,
                              void* d_out, int out_size, void* d_ws, size_t ws_size,
                              hipStream_t stream) {
    const float* emb    = (const float*)d_in[0];
    const float* protos = (const float*)d_in[1];
    const int*   cid    = (const int*)d_in[2];
    float* out = (float*)d_out;

    char* ws = (char*)d_ws;
    _Float16* embn = (_Float16*)ws;                                   // 4 MB
    _Float16* pron = (_Float16*)(ws + ((size_t)4 << 20));             // 2 MB
    float* s_glob  = (float*)(ws + ((size_t)6 << 20));                // 32 KB
    float* terms   = (float*)(ws + ((size_t)6 << 20) + 32768);        // 32 KB
    int*   offs    = (int*)(ws + ((size_t)6 << 20) + 65536);          // 16 KB + 4
    int*   slist   = (int*)(ws + ((size_t)6 << 20) + 98304);          // 32 KB
    int*   counts  = (int*)(ws + ((size_t)6 << 20) + 131072);         // 16 KB
    int*   hist    = (int*)(ws + ((size_t)7 << 20));                  // 512 KB
    int*   pref    = (int*)(ws + ((size_t)7 << 20) + 524288);         // 512 KB

    norm_hist_kernel<<<(Bn + Pn) / 4, 256, 0, stream>>>(emb, protos, cid, embn, pron, s_glob, hist);
    gemm_expsum_kernel<<<dim3(Bn / 128, Pn / 128), 256, 0, stream>>>(embn, pron, s_glob);
    loss_terms_kernel<<<Bn / 4, 256, 0, stream>>>(embn, pron, cid, s_glob, terms);
    counts_pref_kernel<<<Pn / 256, 256, 0, stream>>>(hist, counts, pref);
    offsets_kernel<<<1, 256, 0, stream>>>(counts, offs);
    rankfill_kernel<<<Bn / 256, 256, 0, stream>>>(cid, pref, offs, slist);
    update_loss_kernel<<<Pn / 4, 256, 0, stream>>>(protos, emb, offs, slist, terms, out);
}

// Round 17
// 123.867 us; speedup vs baseline: 1.1159x; 1.1159x over previous
//
#include <hip/hip_runtime.h>
#include <hip/hip_bf16.h>
#include <math.h>

#define Bn 8192
#define Dn 256
#define Pn 4096

// embn rows are scaled by SCALE so the MFMA accumulator is directly the
// base-2 exponent: acc = sim * log2(e)/TEMP.  exp(sim/TEMP) = 2^acc = one v_exp_f32.
#define SCALE 2.8853900817779268f   // log2(e) / TEMP
#define LN2   0.6931471805599453f

using f16x8 = _Float16 __attribute__((ext_vector_type(8)));
using f16x4 = _Float16 __attribute__((ext_vector_type(4)));
using f32x16 = float __attribute__((ext_vector_type(16)));

// FRAGMENT-MAJOR global layout for embn/pron (eliminates the 32-line scatter
// that R12-R16 showed invariant at ~45us): element (row r, k) lives at
//   fm[(r>>5)*8192 + (k>>4)*512 + ((r&31) + 32*((k>>3)&1))*8 + (k&7)]
// so a wave-load of one (tile,kk) fragment is a contiguous 1 KB.
__device__ __forceinline__ size_t fm_off(int r, int L /*lane, k=4L..4L+3*/) {
    return (size_t)(r >> 5) * 8192 + (size_t)(L >> 2) * 512
         + (size_t)((r & 31) + 32 * ((L >> 1) & 1)) * 8 + (L & 1) * 4;
}

// ------- normalize rows (fp32 -> f16 fragment-major; emb scaled) + hist + zero s_glob -------
__global__ void norm_hist_kernel(const float* __restrict__ emb, const float* __restrict__ protos,
                                 const int* __restrict__ cid,
                                 _Float16* __restrict__ embn, _Float16* __restrict__ pron,
                                 float* __restrict__ s_glob, int* __restrict__ hist) {
    __shared__ int h[Pn];
    int gid  = blockIdx.x;
    bool do_hist = (gid < Bn / 256);
    if (do_hist)
        for (int c = threadIdx.x; c < Pn; c += 256) h[c] = 0;

    int row  = gid * 4 + (threadIdx.x >> 6);
    int lane = threadIdx.x & 63;
    const float* in;
    _Float16* out;
    int r;
    float post;
    if (row < Bn) { in = emb;    out = embn; r = row;      post = SCALE; }
    else          { in = protos; out = pron; r = row - Bn; post = 1.0f;  }
    const float4 v = reinterpret_cast<const float4*>(in + (size_t)r * Dn)[lane];
    float ss = v.x * v.x + v.y * v.y + v.z * v.z + v.w * v.w;
#pragma unroll
    for (int m = 1; m <= 32; m <<= 1) ss += __shfl_xor(ss, m);
    float scale = post / fmaxf(sqrtf(ss), 1e-12f);
    f16x4 o;
    o[0] = (_Float16)(v.x * scale);
    o[1] = (_Float16)(v.y * scale);
    o[2] = (_Float16)(v.z * scale);
    o[3] = (_Float16)(v.w * scale);
    *reinterpret_cast<f16x4*>(out + fm_off(r, lane)) = o;

    if (gid < 32) s_glob[gid * 256 + threadIdx.x] = 0.0f;   // zero all 8192 rows

    if (do_hist) {
        __syncthreads();
        atomicAdd(&h[cid[gid * 256 + threadIdx.x]], 1);
        __syncthreads();
        for (int c = threadIdx.x; c < Pn; c += 256)
            hist[gid * Pn + c] = h[c];
    }
}

// ---------------- GEMM + exp-sum: s[row] = sum_p 2^acc ----------------
// Block = 128 rows x 128 cols, 4 waves x 32 rows, 32x32x16 MFMA.
// With fragment-major inputs, A-loads are coalesced 1KB wave-loads and the
// whole 64KB B panel stages as a LINEAR memcpy via global_load_lds
// (source = pron_fm + blockIdx.y*32768 + g*512 + lane*8). One barrier.
__global__ __launch_bounds__(256, 2)
void gemm_expsum_kernel(const _Float16* __restrict__ embn, const _Float16* __restrict__ pron,
                        float* __restrict__ s_glob) {
    __shared__ _Float16 Bs[64 * 512];     // 64 KB: granule g -> Bs + g*1024(B) + lane*16(B)
    const int w    = threadIdx.x >> 6;
    const int lane = threadIdx.x & 63;
    const int lo   = lane & 31;
    const int hi   = lane >> 5;
    const int rbase = blockIdx.x * 128 + w * 32;

    // Stage ALL 64 granules: linear 64 KB copy, 16 loads per wave back-to-back.
    const _Float16* psrc = pron + (size_t)blockIdx.y * 32768 + (size_t)lane * 8;
#pragma unroll
    for (int i = 0; i < 16; ++i) {
        int g = w * 16 + i;
        __builtin_amdgcn_global_load_lds(
            (const __attribute__((address_space(1))) unsigned int*)(psrc + (size_t)g * 512),
            (__attribute__((address_space(3))) unsigned int*)((char*)Bs + (g << 10)),
            16, 0, 0);
    }

    // A fragments: coalesced — tile t = blockIdx.x*4 + w, 16 x 1KB wave-loads.
    const _Float16* ap = embn + (size_t)(blockIdx.x * 4 + w) * 8192 + (size_t)lane * 8;
    f16x8 a[16];
#pragma unroll
    for (int kk = 0; kk < 16; ++kk)
        a[kk] = *reinterpret_cast<const f16x8*>(ap + kk * 512);

    float s[16];
#pragma unroll
    for (int r = 0; r < 16; ++r) s[r] = 0.0f;

    __syncthreads();   // the ONLY barrier: staged B + a[] resident

#pragma unroll
    for (int ct = 0; ct < 4; ++ct) {
        f32x16 acc;
#pragma unroll
        for (int r = 0; r < 16; ++r) acc[r] = 0.0f;
#pragma unroll
        for (int kk = 0; kk < 16; ++kk) {
            f16x8 b = *reinterpret_cast<const f16x8*>(
                (const char*)Bs + ((ct * 16 + kk) << 10) + (lane << 4));  // lane-linear
            acc = __builtin_amdgcn_mfma_f32_32x32x16_f16(a[kk], b, acc, 0, 0, 0);
        }
#pragma unroll
        for (int r = 0; r < 16; ++r)
            s[r] += __builtin_amdgcn_exp2f(acc[r]);   // acc IS the base-2 exponent
    }

    // C/D: col = lo, row = (r&3)+8*(r>>2)+4*hi. Sum over the 32 col-lanes.
#pragma unroll
    for (int r = 0; r < 16; ++r) {
        float v = s[r];
        v += __shfl_xor(v, 1);
        v += __shfl_xor(v, 2);
        v += __shfl_xor(v, 4);
        v += __shfl_xor(v, 8);
        v += __shfl_xor(v, 16);
        if (lo == 0) {
            int row = rbase + (r & 3) + 8 * (r >> 2) + 4 * hi;
            atomicAdd(&s_glob[row], v);
        }
    }
}

// ------- loss terms: term = ln(S_all - 2^accp) - ln2*accp  (fm-layout gather) -------
__global__ void loss_terms_kernel(const _Float16* __restrict__ embn, const _Float16* __restrict__ pron,
                                  const int* __restrict__ cid, const float* __restrict__ s_glob,
                                  float* __restrict__ terms) {
    int row  = blockIdx.x * 4 + (threadIdx.x >> 6);
    int lane = threadIdx.x & 63;
    int c = cid[row];
    f16x4 e = *reinterpret_cast<const f16x4*>(embn + fm_off(row, lane));
    f16x4 p = *reinterpret_cast<const f16x4*>(pron + fm_off(c, lane));
    float d = 0.0f;
#pragma unroll
    for (int j = 0; j < 4; ++j) d += (float)e[j] * (float)p[j];
#pragma unroll
    for (int m = 1; m <= 32; m <<= 1) d += __shfl_xor(d, m);
    if (lane == 0) {
        float accp = d;                                        // = pos_sim * log2(e)/TEMP
        float sneg = s_glob[row] - __builtin_amdgcn_exp2f(accp);  // remove positive column
        terms[row] = __logf(sneg) - LN2 * accp;                // = ln(sneg) - pos_sim/TEMP
    }
}

// ------- counts + per-chunk prefix (parallel, 16 blocks) -------
__global__ void counts_pref_kernel(const int* __restrict__ hist, int* __restrict__ counts,
                                   int* __restrict__ pref) {
    int c = blockIdx.x * 256 + threadIdx.x;
    int s = 0;
#pragma unroll
    for (int ch = 0; ch < 32; ++ch) {
        pref[ch * Pn + c] = s;
        s += hist[ch * Pn + c];
    }
    counts[c] = s;
}

// ------- exclusive scan of counts[4096] -> offs (one block, 256 thr x 16) -------
__global__ void offsets_kernel(const int* __restrict__ counts, int* __restrict__ offs) {
    __shared__ int wtot[4];
    int t = threadIdx.x;
    int local[16];
    int run = 0;
#pragma unroll
    for (int j = 0; j < 16; ++j) { local[j] = run; run += counts[t * 16 + j]; }
    int v = run;
#pragma unroll
    for (int d = 1; d < 64; d <<= 1) {
        int u = __shfl_up(v, d);
        if ((t & 63) >= d) v += u;
    }
    if ((t & 63) == 63) wtot[t >> 6] = v;
    __syncthreads();
    int add = 0;
    for (int ww = 0; ww < (t >> 6); ++ww) add += wtot[ww];
    int excl = add + v - run;
#pragma unroll
    for (int j = 0; j < 16; ++j) offs[t * 16 + j] = excl + local[j];
    if (t == 0) offs[Pn] = Bn;
}

// ------- rank within cluster (deterministic) + CSR fill -------
__global__ void rankfill_kernel(const int* __restrict__ cid, const int* __restrict__ pref,
                                const int* __restrict__ offs, int* __restrict__ slist) {
    __shared__ int ids[256];
    int t = threadIdx.x, g = blockIdx.x;
    int i = g * 256 + t;
    int my = cid[i];
    ids[t] = my;
    __syncthreads();
    int r = pref[g * Pn + my];
    for (int j = 0; j < t; ++j) r += (ids[j] == my) ? 1 : 0;
    slist[offs[my] + r] = i;
}

// ------- EMA gather (one wave per cluster) + loss mean on block 0 -------
__global__ void update_loss_kernel(const float* __restrict__ protos, const float* __restrict__ emb,
                                   const int* __restrict__ offs, const int* __restrict__ slist,
                                   const float* __restrict__ terms, float* __restrict__ out) {
    __shared__ float ws2[4];
    float* outp = out + 1;
    int w = threadIdx.x >> 6, lane = threadIdx.x & 63;
    int c = blockIdx.x * 4 + w;
    int off = offs[c], cnt = offs[c + 1] - off;
    float4 p = reinterpret_cast<const float4*>(protos + (size_t)c * Dn)[lane];
    float scale = __powf(0.9f, (float)cnt);
    float4 acc;
    acc.x = p.x * scale; acc.y = p.y * scale; acc.z = p.z * scale; acc.w = p.w * scale;
    for (int j = 0; j < cnt; ++j) {
        int i = slist[off + j];
        float wgt = 0.1f * __powf(0.9f, (float)(cnt - 1 - j));
        float4 e = reinterpret_cast<const float4*>(emb + (size_t)i * Dn)[lane];
        acc.x += wgt * e.x; acc.y += wgt * e.y; acc.z += wgt * e.z; acc.w += wgt * e.w;
    }
    reinterpret_cast<float4*>(outp + (size_t)c * Dn)[lane] = acc;

    if (blockIdx.x == 0) {
        float ssum = 0.0f;
        for (int i = threadIdx.x; i < Bn; i += 256) ssum += terms[i];
#pragma unroll
        for (int m = 1; m <= 32; m <<= 1) ssum += __shfl_xor(ssum, m);
        if ((threadIdx.x & 63) == 0) ws2[threadIdx.x >> 6] = ssum;
        __syncthreads();
        if (threadIdx.x == 0)
            out[0] = (ws2[0] + ws2[1] + ws2[2] + ws2[3]) * (1.0f / (float)Bn);
    }
}

extern "C" void kernel_launch(void* const* d_in, const int* in_sizes, int n_in,
                              void* d_out, int out_size, void* d_ws, size_t ws_size,
                              hipStream_t stream) {
    const float* emb    = (const float*)d_in[0];
    const float* protos = (const float*)d_in[1];
    const int*   cid    = (const int*)d_in[2];
    float* out = (float*)d_out;

    char* ws = (char*)d_ws;
    _Float16* embn = (_Float16*)ws;                                   // 4 MB (fragment-major)
    _Float16* pron = (_Float16*)(ws + ((size_t)4 << 20));             // 2 MB (fragment-major)
    float* s_glob  = (float*)(ws + ((size_t)6 << 20));                // 32 KB
    float* terms   = (float*)(ws + ((size_t)6 << 20) + 32768);        // 32 KB
    int*   offs    = (int*)(ws + ((size_t)6 << 20) + 65536);          // 16 KB + 4
    int*   slist   = (int*)(ws + ((size_t)6 << 20) + 98304);          // 32 KB
    int*   counts  = (int*)(ws + ((size_t)6 << 20) + 131072);         // 16 KB
    int*   hist    = (int*)(ws + ((size_t)7 << 20));                  // 512 KB
    int*   pref    = (int*)(ws + ((size_t)7 << 20) + 524288);         // 512 KB

    norm_hist_kernel<<<(Bn + Pn) / 4, 256, 0, stream>>>(emb, protos, cid, embn, pron, s_glob, hist);
    gemm_expsum_kernel<<<dim3(Bn / 128, Pn / 128), 256, 0, stream>>>(embn, pron, s_glob);
    loss_terms_kernel<<<Bn / 4, 256, 0, stream>>>(embn, pron, cid, s_glob, terms);
    counts_pref_kernel<<<Pn / 256, 256, 0, stream>>>(hist, counts, pref);
    offsets_kernel<<<1, 256, 0, stream>>>(counts, offs);
    rankfill_kernel<<<Bn / 256, 256, 0, stream>>>(cid, pref, offs, slist);
    update_loss_kernel<<<Pn / 4, 256, 0, stream>>>(protos, emb, offs, slist, terms, out);
}